// Round 1
// baseline (394.919 us; speedup 1.0000x reference)
//
#include <hip/hip_runtime.h>
#include <stdint.h>

typedef unsigned int uint;
typedef unsigned short ushort;

#define GD   96
#define GD2  (GD*GD)           // 9216
#define GSP  (GD*GD*GD)        // 884736 spatial cells
#define NPTS 1000000
#define WIN_ELTS 8192          // padded w_in frags: 64x128
#define WH_ELTS  16384         // 128x128
#define WFRAG_OFF (GSP*16)     // ushort offset of weight frags in ws

#define PW   128               // points per wave
#define ROWB 272               // activation row stride bytes (136 bf16: 128 + 8 pad)
#define LDS_BYTES (4*PW*ROWB)  // 139264

typedef __attribute__((ext_vector_type(8))) short short8;
typedef __attribute__((ext_vector_type(4))) float f32x4;

__device__ __forceinline__ uint f2bf(float x) {           // fp32 -> bf16 (RNE)
  uint u = __float_as_uint(x);
  return (u + 0x7fffu + ((u >> 16) & 1u)) >> 16;
}

// ---- pre-pass 1: feature grid [C,D,H,W] f32 -> [D,H,W,C] bf16 ----
__global__ void k_grid_pack(const float* __restrict__ g, ushort* __restrict__ o) {
  int sp = blockIdx.x * 256 + threadIdx.x;   // 0..884735
  uint pk[8];
#pragma unroll
  for (int c = 0; c < 16; c += 2) {
    float a = g[(size_t)c * GSP + sp];
    float b = g[(size_t)(c + 1) * GSP + sp];
    pk[c >> 1] = f2bf(a) | (f2bf(b) << 16);
  }
  uint4* dst = (uint4*)(o + (size_t)sp * 16);
  dst[0] = make_uint4(pk[0], pk[1], pk[2], pk[3]);
  dst[1] = make_uint4(pk[4], pk[5], pk[6], pk[7]);
}

// ---- pre-pass 2: weights -> MFMA B-fragment-packed bf16 ----
// frag layout: [fragblock][lane=64][j=8], B[k = s*32 + (lane>>4)*8 + j][n = t*16 + (lane&15)]
// w_in: fragblock = t*2+s (K=64 padded, zeros for k>=52); w_h[l]: fragblock = t*4+s
__global__ void k_w_pack(const float* __restrict__ win, const float* __restrict__ h0,
                         const float* __restrict__ h1, const float* __restrict__ h2,
                         ushort* __restrict__ o) {
  int tid = blockIdx.x * 256 + threadIdx.x;  // < 57344
  int lane = (tid >> 3) & 63, j = tid & 7;
  int q = lane >> 4, cc = lane & 15;
  float v;
  if (tid < WIN_ELTS) {
    int blk = tid >> 9;
    int t = blk >> 1, s = blk & 1;
    int k = s * 32 + q * 8 + j, n = t * 16 + cc;
    v = (k < 52) ? win[k * 128 + n] : 0.f;
  } else {
    int f2 = tid - WIN_ELTS;
    int l = f2 >> 14, r = f2 & 16383;
    int blk = r >> 9;
    int t = blk >> 2, s = blk & 3;
    int k = s * 32 + q * 8 + j, n = t * 16 + cc;
    const float* w = (l == 0) ? h0 : ((l == 1) ? h1 : h2);
    v = w[k * 128 + n];
  }
  o[tid] = (ushort)f2bf(v);
}

#define ACC8(off, U, W) {                                  \
  fv[(off)+0] += (W) * __uint_as_float((U).x << 16);       \
  fv[(off)+1] += (W) * __uint_as_float((U).x & 0xffff0000u);\
  fv[(off)+2] += (W) * __uint_as_float((U).y << 16);       \
  fv[(off)+3] += (W) * __uint_as_float((U).y & 0xffff0000u);\
  fv[(off)+4] += (W) * __uint_as_float((U).z << 16);       \
  fv[(off)+5] += (W) * __uint_as_float((U).z & 0xffff0000u);\
  fv[(off)+6] += (W) * __uint_as_float((U).w << 16);       \
  fv[(off)+7] += (W) * __uint_as_float((U).w & 0xffff0000u);\
}

#define MFMA(A,B,C) __builtin_amdgcn_mfma_f32_16x16x32_bf16((A),(B),(C),0,0,0)

// ---- main fused kernel: 4 waves x 128 pts/wave; waves fully independent ----
__global__ __launch_bounds__(256, 1) void k_main(
    const float* __restrict__ x, const float* __restrict__ wout,
    const ushort* __restrict__ gridb, const ushort* __restrict__ wfrag,
    float* __restrict__ out) {
  extern __shared__ char smem[];
  const int wave = threadIdx.x >> 6;
  const int lane = threadIdx.x & 63;
  const int q = lane >> 4, c = lane & 15;
  char* act = smem + wave * (PW * ROWB);
  const int base = blockIdx.x * (4 * PW) + wave * PW;

  // ======== gather + positional encoding: 2 points per lane ========
#pragma unroll
  for (int pp = 0; pp < 2; ++pp) {
    const int p = pp * 64 + lane;
    const int gp = base + p;
    const int gpc = min(gp, NPTS - 1);
    const float px = x[gpc * 3 + 0];
    const float py = x[gpc * 3 + 1];
    const float pz = x[gpc * 3 + 2];
    float fx = (px + 1.0f) * 0.5f * 95.0f;   // x -> W
    float fy = (py + 1.0f) * 0.5f * 95.0f;   // y -> H
    float fz = (pz + 1.0f) * 0.5f * 95.0f;   // z -> D
    float x0f = floorf(fx), y0f = floorf(fy), z0f = floorf(fz);
    float tx = fx - x0f, ty = fy - y0f, tz = fz - z0f;
    int x0i = min(max((int)x0f, 0), 95);
    int y0i = min(max((int)y0f, 0), 95);
    int z0i = min(max((int)z0f, 0), 95);
    int x1i = min(x0i + 1, 95);
    int y1i = min(y0i + 1, 95);
    int z1i = min(z0i + 1, 95);
    float fv[16];
#pragma unroll
    for (int k = 0; k < 16; ++k) fv[k] = 0.f;
#pragma unroll
    for (int dz = 0; dz < 2; ++dz) {
      const int zi = dz ? z1i : z0i;
      const float wz = dz ? tz : (1.f - tz);
#pragma unroll
      for (int dy = 0; dy < 2; ++dy) {
        const int yi = dy ? y1i : y0i;
        const float wzy = wz * (dy ? ty : (1.f - ty));
        const ushort* r0 = gridb + (size_t)(zi * GD2 + yi * GD + x0i) * 16;
        const ushort* r1 = gridb + (size_t)(zi * GD2 + yi * GD + x1i) * 16;
        uint4 a0 = *(const uint4*)r0;
        uint4 a1 = *(const uint4*)(r0 + 8);
        uint4 b0 = *(const uint4*)r1;
        uint4 b1 = *(const uint4*)(r1 + 8);
        const float w0 = wzy * (1.f - tx), w1 = wzy * tx;
        ACC8(0, a0, w0); ACC8(8, a1, w0);
        ACC8(0, b0, w1); ACC8(8, b1, w1);
      }
    }
    float row[64];
#pragma unroll
    for (int i = 0; i < 6; ++i) {
      const float fr = 3.14159265358979323846f * (float)(1 << i);
      row[i*6+0] = __sinf(px*fr); row[i*6+1] = __sinf(py*fr); row[i*6+2] = __sinf(pz*fr);
      row[i*6+3] = __cosf(px*fr); row[i*6+4] = __cosf(py*fr); row[i*6+5] = __cosf(pz*fr);
    }
#pragma unroll
    for (int k = 0; k < 16; ++k) row[36 + k] = fv[k];
#pragma unroll
    for (int k = 52; k < 64; ++k) row[k] = 0.f;
    char* dst = act + p * ROWB;
#pragma unroll
    for (int k = 0; k < 64; k += 8) {
      uint u0 = f2bf(row[k+0]) | (f2bf(row[k+1]) << 16);
      uint u1 = f2bf(row[k+2]) | (f2bf(row[k+3]) << 16);
      uint u2 = f2bf(row[k+4]) | (f2bf(row[k+5]) << 16);
      uint u3 = f2bf(row[k+6]) | (f2bf(row[k+7]) << 16);
      *(uint4*)(dst + k * 2) = make_uint4(u0, u1, u2, u3);
    }
  }
  asm volatile("s_waitcnt lgkmcnt(0)" ::: "memory");

  // ======== layer-in: X[128x64] @ w_in[64x128] -> relu -> act ========
  {
    short8 bw[16];
#pragma unroll
    for (int f = 0; f < 16; ++f)
      bw[f] = *(const short8*)(wfrag + f * 512 + lane * 8);
    for (int mt = 0; mt < 8; ++mt) {
      const char* arow = act + (mt * 16 + c) * ROWB + q * 16;
      short8 a0 = *(const short8*)(arow);
      short8 a1 = *(const short8*)(arow + 64);
      f32x4 av[8];
#pragma unroll
      for (int t = 0; t < 8; ++t) av[t] = f32x4{0.f, 0.f, 0.f, 0.f};
#pragma unroll
      for (int t = 0; t < 8; ++t) {
        av[t] = MFMA(a0, bw[t*2+0], av[t]);
        av[t] = MFMA(a1, bw[t*2+1], av[t]);
      }
      asm volatile("s_waitcnt lgkmcnt(0)" ::: "memory");
      char* yb = act + (mt * 16 + q * 4) * ROWB + c * 2;
#pragma unroll
      for (int t = 0; t < 8; ++t)
#pragma unroll
        for (int r = 0; r < 4; ++r)
          *(ushort*)(yb + r * ROWB + t * 32) = (ushort)f2bf(fmaxf(av[t][r], 0.f));
    }
  }
  asm volatile("s_waitcnt lgkmcnt(0)" ::: "memory");

  // ======== hidden layers h0,h1 (relu->act) and h2 (+w_out dot, store) ========
  for (int l = 0; l < 3; ++l) {
    const ushort* wl = wfrag + WIN_ELTS + l * WH_ELTS;
    short8 bw[32];
#pragma unroll
    for (int f = 0; f < 32; ++f)
      bw[f] = *(const short8*)(wl + f * 512 + lane * 8);
    if (l < 2) {
      for (int mt = 0; mt < 8; ++mt) {
        const char* arow = act + (mt * 16 + c) * ROWB + q * 16;
        short8 a0 = *(const short8*)(arow);
        short8 a1 = *(const short8*)(arow + 64);
        short8 a2 = *(const short8*)(arow + 128);
        short8 a3 = *(const short8*)(arow + 192);
        f32x4 av[8];
#pragma unroll
        for (int t = 0; t < 8; ++t) av[t] = f32x4{0.f, 0.f, 0.f, 0.f};
#pragma unroll
        for (int t = 0; t < 8; ++t) {
          av[t] = MFMA(a0, bw[t*4+0], av[t]);
          av[t] = MFMA(a1, bw[t*4+1], av[t]);
          av[t] = MFMA(a2, bw[t*4+2], av[t]);
          av[t] = MFMA(a3, bw[t*4+3], av[t]);
        }
        asm volatile("s_waitcnt lgkmcnt(0)" ::: "memory");
        char* yb = act + (mt * 16 + q * 4) * ROWB + c * 2;
#pragma unroll
        for (int t = 0; t < 8; ++t)
#pragma unroll
          for (int r = 0; r < 4; ++r)
            *(ushort*)(yb + r * ROWB + t * 32) = (ushort)f2bf(fmaxf(av[t][r], 0.f));
      }
      asm volatile("s_waitcnt lgkmcnt(0)" ::: "memory");
    } else {
      float wo[8];
#pragma unroll
      for (int t = 0; t < 8; ++t) wo[t] = wout[t * 16 + c];
      for (int mt = 0; mt < 8; ++mt) {
        const char* arow = act + (mt * 16 + c) * ROWB + q * 16;
        short8 a0 = *(const short8*)(arow);
        short8 a1 = *(const short8*)(arow + 64);
        short8 a2 = *(const short8*)(arow + 128);
        short8 a3 = *(const short8*)(arow + 192);
        f32x4 av[8];
#pragma unroll
        for (int t = 0; t < 8; ++t) av[t] = f32x4{0.f, 0.f, 0.f, 0.f};
#pragma unroll
        for (int t = 0; t < 8; ++t) {
          av[t] = MFMA(a0, bw[t*4+0], av[t]);
          av[t] = MFMA(a1, bw[t*4+1], av[t]);
          av[t] = MFMA(a2, bw[t*4+2], av[t]);
          av[t] = MFMA(a3, bw[t*4+3], av[t]);
        }
#pragma unroll
        for (int r = 0; r < 4; ++r) {
          float y = 0.f;
#pragma unroll
          for (int t = 0; t < 8; ++t) y += fmaxf(av[t][r], 0.f) * wo[t];
          y += __shfl_xor(y, 1, 64);
          y += __shfl_xor(y, 2, 64);
          y += __shfl_xor(y, 4, 64);
          y += __shfl_xor(y, 8, 64);
          if (c == r) {
            int gpo = base + mt * 16 + q * 4 + r;
            if (gpo < NPTS) out[gpo] = y;   // VOL scale: *1 + 0
          }
        }
      }
    }
  }
}

extern "C" void kernel_launch(void* const* d_in, const int* in_sizes, int n_in,
                              void* d_out, int out_size, void* d_ws, size_t ws_size,
                              hipStream_t stream) {
  const float* x    = (const float*)d_in[0];
  const float* fg   = (const float*)d_in[1];
  const float* win  = (const float*)d_in[2];
  const float* wh0  = (const float*)d_in[3];
  const float* wh1  = (const float*)d_in[4];
  const float* wh2  = (const float*)d_in[5];
  const float* wout = (const float*)d_in[6];
  float* out = (float*)d_out;

  ushort* gridb = (ushort*)d_ws;                       // 28,311,552 B
  ushort* wfrag = (ushort*)d_ws + WFRAG_OFF;           // +114,688 B

  k_grid_pack<<<GSP / 256, 256, 0, stream>>>(fg, gridb);
  k_w_pack<<<(WIN_ELTS + 3 * WH_ELTS) / 256, 256, 0, stream>>>(win, wh0, wh1, wh2, wfrag);

  const int nblk = (NPTS + 4 * PW - 1) / (4 * PW);     // 1954
  k_main<<<nblk, 256, LDS_BYTES, stream>>>(x, wout, gridb, wfrag, out);
}